// Round 1
// baseline (527.909 us; speedup 1.0000x reference)
//
#include <hip/hip_runtime.h>

#define NN 512
#define DD 128
#define PP (NN*NN)   // 262144 positions

typedef __attribute__((ext_vector_type(8))) short short8;
typedef __attribute__((ext_vector_type(4))) short shortx4;
typedef __attribute__((ext_vector_type(4))) float floatx4;

__device__ __forceinline__ unsigned short f2bf(float f) {
  unsigned int u = __float_as_uint(f);
  u += 0x7fffu + ((u >> 16) & 1u);          // RNE
  return (unsigned short)(u >> 16);
}
__device__ __forceinline__ float bf2f(unsigned short h) {
  return __uint_as_float(((unsigned int)h) << 16);
}
__device__ __forceinline__ float sigm(float x) {
  return 1.f / (1.f + __expf(-x));
}

// async global->LDS, 16B per lane. LDS dest must be wave-uniform base + lane*16.
__device__ __forceinline__ void gload_lds16(const unsigned short* g, unsigned short* l) {
  __builtin_amdgcn_global_load_lds(
      (const __attribute__((address_space(1))) unsigned int*)g,
      (__attribute__((address_space(3))) unsigned int*)l, 16, 0, 0);
}

// ---------------- k0: weights f32 [d][e] -> bf16 [m][e][d] ----------------
__global__ void k0_prep(const float* __restrict__ wlp, const float* __restrict__ wlg,
                        const float* __restrict__ wrp, const float* __restrict__ wrg,
                        const float* __restrict__ wg,  const float* __restrict__ wo,
                        unsigned short* __restrict__ wt) {
  const float* src[6] = {wlp, wlg, wrp, wrg, wg, wo};
  int m = blockIdx.y;
  int idx = blockIdx.x * 256 + threadIdx.x;   // 0..16383
  int d = idx >> 7, e = idx & 127;
  wt[m * 16384 + e * 128 + d] = f2bf(src[m][d * 128 + e]);
}

// ---------------- k1: LN + projections + sigmoid/mask, transposed bf16 stores ----
// unit 0: left_t[e][i*512+j]   (block = 128 consecutive flat positions)
// unit 1: right_bt[e][k*512+j] (block = 128 j's at fixed k -> store B^T layout)
// unit 2: gate_t[e][i*512+k]
__device__ __forceinline__ void run_mm(const unsigned short* __restrict__ wt_m,
                                       unsigned short* Alds, unsigned short* Wlds,
                                       int t, int wm, int we, int ln, int q8,
                                       floatx4 (&acc)[4][4]) {
  #pragma unroll
  for (int it = 0; it < 8; ++it) {            // stage W^T [e][d] pitch 136
    int flat = it * 256 + t;
    int e = flat >> 4, c = flat & 15;
    *(short8*)&Wlds[e * 136 + c * 8] = *(const short8*)(wt_m + e * 128 + c * 8);
  }
  __syncthreads();
  #pragma unroll
  for (int ks = 0; ks < 4; ++ks) {
    short8 a[4], b[4];
    #pragma unroll
    for (int i = 0; i < 4; ++i)
      a[i] = *(const short8*)&Alds[(wm + i * 16 + ln) * 136 + ks * 32 + q8 * 8];
    #pragma unroll
    for (int i = 0; i < 4; ++i)
      b[i] = *(const short8*)&Wlds[(we + i * 16 + ln) * 136 + ks * 32 + q8 * 8];
    #pragma unroll
    for (int i = 0; i < 4; ++i)
      #pragma unroll
      for (int j = 0; j < 4; ++j)
        acc[i][j] = __builtin_amdgcn_mfma_f32_16x16x32_bf16(a[i], b[j], acc[i][j], 0, 0, 0);
  }
  __syncthreads();
}

__launch_bounds__(256, 2)
__global__ void k1_ln_proj(const float* __restrict__ pair, const float* __restrict__ pmask,
                           const float* __restrict__ lng, const float* __restrict__ lnb,
                           const unsigned short* __restrict__ wt,
                           const float* __restrict__ b_lp, const float* __restrict__ b_lg,
                           const float* __restrict__ b_rp, const float* __restrict__ b_rg,
                           const float* __restrict__ b_g,
                           unsigned short* __restrict__ left_t,
                           unsigned short* __restrict__ right_bt,
                           unsigned short* __restrict__ gate_t) {
  __shared__ __align__(16) unsigned short Alds[128 * 136];
  __shared__ __align__(16) unsigned short Wlds[128 * 136];
  __shared__ float Mlds[128];

  const int t = threadIdx.x;
  const int unit = blockIdx.y;
  const int q = blockIdx.x;

  long prow0, pstride, mrow0, mstride, soff;
  if (unit == 1) {
    int j0 = (q >> 9) << 7, k0 = q & 511;
    prow0 = ((long)j0 * NN + k0) * DD; pstride = (long)NN * DD;
    mrow0 = (long)j0 * NN + k0;        mstride = NN;
    soff  = (long)k0 * NN + j0;
  } else {
    long p0 = (long)q << 7;
    prow0 = p0 * DD; pstride = DD;
    mrow0 = p0;      mstride = 1;
    soff  = p0;
  }

  { // LayerNorm: 2 threads per row, 64 ch each; write bf16 A tile [pos][d] pitch 136
    int r = t >> 1, h = t & 1;
    const float* row = pair + prow0 + (long)r * pstride + h * 64;
    floatx4 v[16];
    float s = 0.f, s2 = 0.f;
    #pragma unroll
    for (int c = 0; c < 16; ++c) {
      v[c] = *(const floatx4*)(row + c * 4);
      s  += v[c].x + v[c].y + v[c].z + v[c].w;
      s2 += v[c].x * v[c].x + v[c].y * v[c].y + v[c].z * v[c].z + v[c].w * v[c].w;
    }
    s  += __shfl_xor(s, 1);
    s2 += __shfl_xor(s2, 1);
    float mu = s * (1.f / 128.f);
    float var = s2 * (1.f / 128.f) - mu * mu;
    float rs = rsqrtf(var + 1e-5f);
    #pragma unroll
    for (int c = 0; c < 16; ++c) {
      floatx4 g4 = *(const floatx4*)(lng + h * 64 + c * 4);
      floatx4 b4 = *(const floatx4*)(lnb + h * 64 + c * 4);
      shortx4 pk;
      pk[0] = (short)f2bf((v[c].x - mu) * rs * g4.x + b4.x);
      pk[1] = (short)f2bf((v[c].y - mu) * rs * g4.y + b4.y);
      pk[2] = (short)f2bf((v[c].z - mu) * rs * g4.z + b4.z);
      pk[3] = (short)f2bf((v[c].w - mu) * rs * g4.w + b4.w);
      *(shortx4*)&Alds[r * 136 + h * 64 + c * 4] = pk;
    }
    if (h == 0) Mlds[r] = pmask[mrow0 + (long)r * mstride];
  }
  __syncthreads();

  const int lane = t & 63, w = t >> 6;
  const int ln = lane & 15, q8 = lane >> 4;
  const int wm = (w >> 1) << 6, we = (w & 1) << 6;

  // per-wave 64x72 bf16 staging region (reuses A/W LDS after matmuls)
  unsigned short* stg = (w < 2) ? (Alds + w * 4608) : (Wlds + (w - 2) * 4608);

  if (unit < 2) {
    floatx4 accA[4][4] = {};
    floatx4 accB[4][4] = {};
    run_mm(wt + (unit == 0 ? 0 : 2) * 16384, Alds, Wlds, t, wm, we, ln, q8, accA);
    run_mm(wt + (unit == 0 ? 1 : 3) * 16384, Alds, Wlds, t, wm, we, ln, q8, accB);
    const float* bpp = (unit == 0) ? b_lp : b_rp;
    const float* bgg = (unit == 0) ? b_lg : b_rg;
    #pragma unroll
    for (int j = 0; j < 4; ++j) {
      int eg = we + j * 16 + ln;
      float bp_v = bpp[eg], bg_v = bgg[eg];
      #pragma unroll
      for (int i = 0; i < 4; ++i) {
        shortx4 pk;
        #pragma unroll
        for (int r = 0; r < 4; ++r) {
          int m = wm + i * 16 + q8 * 4 + r;
          float val = (accA[i][j][r] + bp_v) * sigm(accB[i][j][r] + bg_v) * Mlds[m];
          pk[r] = (short)f2bf(val);
        }
        *(shortx4*)&stg[(j * 16 + ln) * 72 + i * 16 + q8 * 4] = pk;  // [e][m]
      }
    }
  } else {
    floatx4 accA[4][4] = {};
    run_mm(wt + 4 * 16384, Alds, Wlds, t, wm, we, ln, q8, accA);
    #pragma unroll
    for (int j = 0; j < 4; ++j) {
      int eg = we + j * 16 + ln;
      float bg_v = b_g[eg];
      #pragma unroll
      for (int i = 0; i < 4; ++i) {
        shortx4 pk;
        #pragma unroll
        for (int r = 0; r < 4; ++r)
          pk[r] = (short)f2bf(sigm(accA[i][j][r] + bg_v));
        *(shortx4*)&stg[(j * 16 + ln) * 72 + i * 16 + q8 * 4] = pk;
      }
    }
  }
  __syncthreads();

  unsigned short* dstbase = (unit == 0) ? left_t : (unit == 1 ? right_bt : gate_t);
  #pragma unroll
  for (int itr = 0; itr < 8; ++itr) {       // coalesced transposed store: rows = e
    int row = itr * 8 + (lane >> 3);
    int c = lane & 7;
    short8 vv = *(const short8*)&stg[row * 72 + c * 8];
    long eg = we + row;
    *(short8*)(dstbase + eg * PP + soff + wm + c * 8) = vv;
  }
}

// ---------------- k2: per-channel 512^3 bf16 GEMM + gate, m97 structure -------
__launch_bounds__(256, 3)
__global__ void k2_einsum(const unsigned short* __restrict__ left_t,
                          const unsigned short* __restrict__ right_bt,
                          const unsigned short* __restrict__ gate_t,
                          unsigned short* __restrict__ tmpg) {
  __shared__ __align__(16) unsigned short Al[128 * 32];
  __shared__ __align__(16) unsigned short Bl[128 * 32];
  const int t = threadIdx.x;
  const int d = blockIdx.y;
  const int i0 = (blockIdx.x >> 2) << 7;
  const int k0 = (blockIdx.x & 3) << 7;
  const unsigned short* Ag = left_t   + (long)d * PP;  // [i][j]
  const unsigned short* Bg = right_bt + (long)d * PP;  // [k][j]  (B^T)
  const int lane = t & 63, w = t >> 6;
  const int ln = lane & 15, q8 = lane >> 4;
  const int wm = (w >> 1) << 6, wn = (w & 1) << 6;

  floatx4 acc[4][4] = {};
  for (int j0 = 0; j0 < NN; j0 += 32) {
    #pragma unroll
    for (int it = 0; it < 2; ++it) {
      int flat = it * 256 + t;
      int r = flat >> 2, c = flat & 3;
      gload_lds16(Ag + (long)(i0 + r) * NN + j0 + c * 8, &Al[flat * 8]);
    }
    #pragma unroll
    for (int it = 0; it < 2; ++it) {
      int flat = it * 256 + t;
      int r = flat >> 2, c = flat & 3;
      gload_lds16(Bg + (long)(k0 + r) * NN + j0 + c * 8, &Bl[flat * 8]);
    }
    __syncthreads();
    short8 a[4], b[4];
    #pragma unroll
    for (int i = 0; i < 4; ++i)
      a[i] = *(const short8*)&Al[(wm + i * 16 + ln) * 32 + q8 * 8];
    #pragma unroll
    for (int i = 0; i < 4; ++i)
      b[i] = *(const short8*)&Bl[(wn + i * 16 + ln) * 32 + q8 * 8];
    #pragma unroll
    for (int i = 0; i < 4; ++i)
      #pragma unroll
      for (int j = 0; j < 4; ++j)
        acc[i][j] = __builtin_amdgcn_mfma_f32_16x16x32_bf16(a[i], b[j], acc[i][j], 0, 0, 0);
    __syncthreads();
  }
  const unsigned short* Gg = gate_t + (long)d * PP;
  unsigned short* Og = tmpg + (long)d * PP;
  #pragma unroll
  for (int i = 0; i < 4; ++i)
    #pragma unroll
    for (int j = 0; j < 4; ++j) {
      int n = k0 + wn + j * 16 + ln;
      #pragma unroll
      for (int r = 0; r < 4; ++r) {
        int m = i0 + wm + i * 16 + q8 * 4 + r;
        long idx = (long)m * NN + n;
        Og[idx] = f2bf(acc[i][j][r] * bf2f(Gg[idx]));
      }
    }
}

// ---------------- k3: out[p][e] = sum_d tmpg[d][p]*wo[d][e] + b_o -------------
__launch_bounds__(256, 2)
__global__ void k3_out(const unsigned short* __restrict__ tmpg,
                       const unsigned short* __restrict__ wt,
                       const float* __restrict__ b_o,
                       float* __restrict__ out) {
  __shared__ __align__(16) unsigned short Tl[128 * 136];  // [d][p_local]
  __shared__ __align__(16) unsigned short Wl[128 * 136];  // [e][d]
  const int t = threadIdx.x;
  const long p0 = (long)blockIdx.x << 7;
  const unsigned short* wo = wt + 5 * 16384;

  #pragma unroll
  for (int it = 0; it < 8; ++it) {
    int flat = it * 256 + t;
    int e = flat >> 4, c = flat & 15;
    *(short8*)&Wl[e * 136 + c * 8] = *(const short8*)(wo + e * 128 + c * 8);
  }
  #pragma unroll
  for (int it = 0; it < 8; ++it) {
    int flat = it * 256 + t;
    int dd2 = flat >> 4, c = flat & 15;
    *(short8*)&Tl[dd2 * 136 + c * 8] = *(const short8*)(tmpg + (long)dd2 * PP + p0 + c * 8);
  }
  __syncthreads();

  const int lane = t & 63, w = t >> 6;
  const int ln = lane & 15, q8 = lane >> 4;
  const int wm = (w >> 1) << 6, wn = (w & 1) << 6;

  floatx4 acc[4][4] = {};
  #pragma unroll
  for (int ks = 0; ks < 4; ++ks) {
    short8 a[4], b[4];
    #pragma unroll
    for (int i = 0; i < 4; ++i) {     // gather A-frag from [d][p] (K strided)
      int m = wm + i * 16 + ln;
      short8 av;
      #pragma unroll
      for (int jj = 0; jj < 8; ++jj)
        av[jj] = (short)Tl[(ks * 32 + q8 * 8 + jj) * 136 + m];
      a[i] = av;
    }
    #pragma unroll
    for (int i = 0; i < 4; ++i)
      b[i] = *(const short8*)&Wl[(wn + i * 16 + ln) * 136 + ks * 32 + q8 * 8];
    #pragma unroll
    for (int i = 0; i < 4; ++i)
      #pragma unroll
      for (int j = 0; j < 4; ++j)
        acc[i][j] = __builtin_amdgcn_mfma_f32_16x16x32_bf16(a[i], b[j], acc[i][j], 0, 0, 0);
  }
  #pragma unroll
  for (int j = 0; j < 4; ++j) {
    int eg = wn + j * 16 + ln;
    float bias = b_o[eg];
    #pragma unroll
    for (int i = 0; i < 4; ++i)
      #pragma unroll
      for (int r = 0; r < 4; ++r) {
        int m = wm + i * 16 + q8 * 4 + r;
        out[(p0 + m) * DD + eg] = acc[i][j][r] + bias;
      }
  }
}

extern "C" void kernel_launch(void* const* d_in, const int* in_sizes, int n_in,
                              void* d_out, int out_size, void* d_ws, size_t ws_size,
                              hipStream_t stream) {
  const float* pair = (const float*)d_in[0];
  const float* pmask = (const float*)d_in[1];
  const float* ln_g = (const float*)d_in[2];
  const float* ln_b = (const float*)d_in[3];
  const float* w_lp = (const float*)d_in[4];
  const float* b_lp = (const float*)d_in[5];
  const float* w_lg = (const float*)d_in[6];
  const float* b_lg = (const float*)d_in[7];
  const float* w_rp = (const float*)d_in[8];
  const float* b_rp = (const float*)d_in[9];
  const float* w_rg = (const float*)d_in[10];
  const float* b_rg = (const float*)d_in[11];
  const float* w_g  = (const float*)d_in[12];
  const float* b_g  = (const float*)d_in[13];
  const float* w_o  = (const float*)d_in[14];
  const float* b_o  = (const float*)d_in[15];
  float* out = (float*)d_out;

  // workspace: wt(192KB) + 4 x 64MB bf16 tensors = ~256.2 MiB
  char* ws = (char*)d_ws;
  unsigned short* wt       = (unsigned short*)ws;
  unsigned short* left_t   = (unsigned short*)(ws + 196608);
  unsigned short* right_bt = left_t   + (size_t)PP * DD;
  unsigned short* gate_t   = right_bt + (size_t)PP * DD;
  unsigned short* tmpg     = gate_t   + (size_t)PP * DD;

  k0_prep<<<dim3(64, 6), 256, 0, stream>>>(w_lp, w_lg, w_rp, w_rg, w_g, w_o, wt);
  k1_ln_proj<<<dim3(2048, 3), 256, 0, stream>>>(pair, pmask, ln_g, ln_b, wt,
      b_lp, b_lg, b_rp, b_rg, b_g, left_t, right_bt, gate_t);
  k2_einsum<<<dim3(16, 128), 256, 0, stream>>>(left_t, right_bt, gate_t, tmpg);
  k3_out<<<dim3(2048), 256, 0, stream>>>(tmpg, wt, b_o, out);
}